// Round 3
// baseline (265.750 us; speedup 1.0000x reference)
//
#include <hip/hip_runtime.h>
#include <cstdint>
#include <cstddef>

typedef __bf16 bf16x8 __attribute__((ext_vector_type(8)));
typedef __bf16 bf16x4 __attribute__((ext_vector_type(4)));
typedef float  f32x4  __attribute__((ext_vector_type(4)));

#define MFMA_BF16(a, b, c) __builtin_amdgcn_mfma_f32_16x16x32_bf16((a), (b), (c), 0, 0, 0)

// ---------------- fp32 -> bf16 conversion (8 elems/thread) ----------------
__global__ void cvt_kernel(const float* __restrict__ s, __bf16* __restrict__ d, int n8) {
  int i = blockIdx.x * blockDim.x + threadIdx.x;
  const int stride = gridDim.x * blockDim.x;
  for (; i < n8; i += stride) {
    const float4* p = (const float4*)(s + (size_t)i * 8);
    float4 a = p[0], b = p[1];
    bf16x8 v;
    v[0] = (__bf16)a.x; v[1] = (__bf16)a.y; v[2] = (__bf16)a.z; v[3] = (__bf16)a.w;
    v[4] = (__bf16)b.x; v[5] = (__bf16)b.y; v[6] = (__bf16)b.z; v[7] = (__bf16)b.w;
    *(bf16x8*)(d + (size_t)i * 8) = v;
  }
}

// ---------------- mask all-zero? (mask is fp32) ----------------
__global__ void maskflag_kernel(const unsigned long long* __restrict__ m, int* __restrict__ flag) {
  const int n64 = 2048 * 2048 * 4 / 8;  // 2,097,152 8-byte chunks
  int idx = blockIdx.x * blockDim.x + threadIdx.x;
  bool nz = false;
  for (int i = idx; i < n64; i += gridDim.x * blockDim.x) nz |= (m[i] != 0ull);
  if (nz) atomicOr(flag, 1);
}

// ---------------- fused QGKV projection (bf16 in, bf16 out, fp32 acc) ----------------
// C[m,n] = sum_k X[m,k] * W[n,k] + b[n];  M=4096, N=4096 (0..1023 Q | ..2047 gate | ..3071 K | ..4095 V)
__global__ __launch_bounds__(256) void proj_kernel(
    const __bf16* __restrict__ X,
    const __bf16* __restrict__ qw, const float* __restrict__ qb,
    const __bf16* __restrict__ kw, const float* __restrict__ kb,
    const __bf16* __restrict__ vw, const float* __restrict__ vb,
    __bf16* __restrict__ Qo, __bf16* __restrict__ Ko,
    __bf16* __restrict__ VTo, __bf16* __restrict__ Go)
{
  __shared__ __bf16 As[128][64];
  __shared__ __bf16 Bs[128][64];

  // XCD swizzle: xcd = bid&7 owns n-tiles [xcd*4, xcd*4+4) -> B panels L2-resident per XCD
  const int bid = blockIdx.x;
  const int r = bid >> 3;
  const int ntile = (bid & 7) * 4 + (r >> 5);
  const int mtile = r & 31;
  const int m0 = mtile * 128;
  const int n0 = ntile * 128;

  const __bf16* W; const float* bias; int nb;
  if (n0 < 2048)      { W = qw; bias = qb; nb = n0; }
  else if (n0 < 3072) { W = kw; bias = kb; nb = n0 - 2048; }
  else                { W = vw; bias = vb; nb = n0 - 3072; }

  const int tid = threadIdx.x;
  const int wv = tid >> 6, ln = tid & 63;
  const int wr = wv >> 1, wc = wv & 1;
  const int qr = ln & 15, qg = ln >> 4;
  const int lrow = ln >> 3, lcol = (ln & 7) * 8;

  f32x4 acc[4][4];
#pragma unroll
  for (int m = 0; m < 4; ++m)
#pragma unroll
    for (int n = 0; n < 4; ++n) acc[m][n] = 0.f;

  for (int k0 = 0; k0 < 1024; k0 += 64) {
#pragma unroll
    for (int i = 0; i < 4; ++i) {
      const int rb = i * 32 + wv * 8;  // this wave's 8-row slab
      bf16x8 va = *(const bf16x8*)(X + (size_t)(m0 + rb + lrow) * 1024 + k0 + lcol);
      bf16x8 vb2 = *(const bf16x8*)(W + (size_t)(nb + rb + lrow) * 1024 + k0 + lcol);
      *(bf16x8*)&As[rb + lrow][lcol] = va;
      *(bf16x8*)&Bs[rb + lrow][lcol] = vb2;
    }
    __syncthreads();
#pragma unroll
    for (int kk = 0; kk < 2; ++kk) {
      bf16x8 af[4], bfv[4];
#pragma unroll
      for (int m = 0; m < 4; ++m) af[m] = *(const bf16x8*)&As[wr * 64 + m * 16 + qr][kk * 32 + qg * 8];
#pragma unroll
      for (int n = 0; n < 4; ++n) bfv[n] = *(const bf16x8*)&Bs[wc * 64 + n * 16 + qr][kk * 32 + qg * 8];
#pragma unroll
      for (int m = 0; m < 4; ++m)
#pragma unroll
        for (int n = 0; n < 4; ++n) acc[m][n] = MFMA_BF16(af[m], bfv[n], acc[m][n]);
    }
    __syncthreads();
  }

  // epilogue: C/D layout col=lane&15, row=(lane>>4)*4+reg
#pragma unroll
  for (int m = 0; m < 4; ++m) {
    const int gm0 = m0 + wr * 64 + m * 16 + qg * 4;  // rows gm0..gm0+3 (reg)
    const int b = gm0 >> 11;
    const int s = gm0 & 2047;
#pragma unroll
    for (int n = 0; n < 4; ++n) {
      const int nl = wc * 64 + n * 16 + qr;  // 0..127 within tile
      const float bb = bias[nb + nl];
      if (n0 < 1024) {            // Q -> [b,h,s,d]
        const int col = n0 + nl, hh = col >> 6, dd = col & 63;
        __bf16* dst = Qo + ((size_t)((b << 4) + hh)) * 131072 + (size_t)s * 64 + dd;
#pragma unroll
        for (int rr = 0; rr < 4; ++rr) dst[(size_t)rr * 64] = (__bf16)(acc[m][n][rr] + bb);
      } else if (n0 < 2048) {     // gate -> sigmoid -> [token, h*64+d]
        const int j = n0 - 1024 + nl;
        __bf16* dst = Go + (size_t)gm0 * 1024 + j;
#pragma unroll
        for (int rr = 0; rr < 4; ++rr) {
          const float v = acc[m][n][rr] + bb;
          dst[(size_t)rr * 1024] = (__bf16)(1.f / (1.f + __expf(-v)));
        }
      } else if (n0 < 3072) {     // K -> [b,h,s,d]
        const int j = n0 - 2048 + nl, hh = j >> 6, dd = j & 63;
        __bf16* dst = Ko + ((size_t)((b << 4) + hh)) * 131072 + (size_t)s * 64 + dd;
#pragma unroll
        for (int rr = 0; rr < 4; ++rr) dst[(size_t)rr * 64] = (__bf16)(acc[m][n][rr] + bb);
      } else {                    // V -> transposed [b,h,d,s], pack 4 consecutive s
        const int j = n0 - 3072 + nl, hh = j >> 6, dd = j & 63;
        bf16x4 pv;
#pragma unroll
        for (int rr = 0; rr < 4; ++rr) pv[rr] = (__bf16)(acc[m][n][rr] + bb);
        *(bf16x4*)(VTo + ((size_t)((b << 4) + hh)) * 131072 + (size_t)dd * 2048 + s) = pv;
      }
    }
  }
}

// ---------------- flash attention, 1 wave / 32 q-rows ----------------
__global__ __launch_bounds__(64, 2) void attn_kernel(
    const __bf16* __restrict__ Qb, const __bf16* __restrict__ Kb,
    const __bf16* __restrict__ VT, const __bf16* __restrict__ G,
    const float* __restrict__ mask, const int* __restrict__ flag,
    __bf16* __restrict__ attn)
{
  __shared__ __bf16 Pt[32][72];  // P transpose buffer, pad 64->72 (2-way banks = free)
  const int bid = blockIdx.x;    // 2048 = 32 heads * 64 q-tiles
  const int y = bid >> 3;        // 0..255
  const int hl = (bid & 7) * 4 + (y >> 6);  // head-linear 0..31; 4 heads per XCD
  const int qt = y & 63;
  const int q0 = qt * 32;
  const int ln = threadIdx.x;
  const int qr = ln & 15, qg = ln >> 4;
  const int b = hl >> 4, h = hl & 15;

  const __bf16* Qh = Qb + (size_t)hl * 131072;
  const __bf16* Kh = Kb + (size_t)hl * 131072;
  const __bf16* Vh = VT + (size_t)hl * 131072;

  bf16x8 qf[2][2];
#pragma unroll
  for (int m = 0; m < 2; ++m)
#pragma unroll
    for (int kk = 0; kk < 2; ++kk)
      qf[m][kk] = *(const bf16x8*)(Qh + (size_t)(q0 + m * 16 + qr) * 64 + kk * 32 + qg * 8);

  f32x4 o[2][4];
  float mrun[2][4], lrun[2][4];
#pragma unroll
  for (int m = 0; m < 2; ++m) {
#pragma unroll
    for (int df = 0; df < 4; ++df) o[m][df] = 0.f;
#pragma unroll
    for (int rr = 0; rr < 4; ++rr) { mrun[m][rr] = -1e30f; lrun[m][rr] = 0.f; }
  }

  const bool um = (*flag) != 0;

  for (int kv0 = 0; kv0 < 2048; kv0 += 64) {
    bf16x8 kf[4][2];
#pragma unroll
    for (int n = 0; n < 4; ++n)
#pragma unroll
      for (int kk = 0; kk < 2; ++kk)
        kf[n][kk] = *(const bf16x8*)(Kh + (size_t)(kv0 + n * 16 + qr) * 64 + kk * 32 + qg * 8);

    f32x4 sacc[2][4];
#pragma unroll
    for (int m = 0; m < 2; ++m)
#pragma unroll
      for (int n = 0; n < 4; ++n) {
        sacc[m][n] = 0.f;
        sacc[m][n] = MFMA_BF16(qf[m][0], kf[n][0], sacc[m][n]);
        sacc[m][n] = MFMA_BF16(qf[m][1], kf[n][1], sacc[m][n]);
      }

    float sv[2][4][4];
#pragma unroll
    for (int m = 0; m < 2; ++m)
#pragma unroll
      for (int n = 0; n < 4; ++n)
#pragma unroll
        for (int rr = 0; rr < 4; ++rr) sv[m][n][rr] = sacc[m][n][rr] * 0.125f;

    if (um) {
#pragma unroll
      for (int m = 0; m < 2; ++m)
#pragma unroll
        for (int rr = 0; rr < 4; ++rr) {
          const int row = q0 + m * 16 + qg * 4 + rr;
#pragma unroll
          for (int n = 0; n < 4; ++n)
            sv[m][n][rr] += mask[(size_t)row * 2048 + kv0 + n * 16 + qr];
        }
    }

    float alpha[2][4];
#pragma unroll
    for (int m = 0; m < 2; ++m)
#pragma unroll
      for (int rr = 0; rr < 4; ++rr) {
        float t = fmaxf(fmaxf(sv[m][0][rr], sv[m][1][rr]), fmaxf(sv[m][2][rr], sv[m][3][rr]));
        t = fmaxf(t, __shfl_xor(t, 1));
        t = fmaxf(t, __shfl_xor(t, 2));
        t = fmaxf(t, __shfl_xor(t, 4));
        t = fmaxf(t, __shfl_xor(t, 8));
        const float mn = fmaxf(mrun[m][rr], t);
        const float al = __expf(mrun[m][rr] - mn);
        mrun[m][rr] = mn;
        float ps = 0.f;
#pragma unroll
        for (int n = 0; n < 4; ++n) {
          const float p = __expf(sv[m][n][rr] - mn);
          sv[m][n][rr] = p;
          ps += p;
        }
        ps += __shfl_xor(ps, 1);
        ps += __shfl_xor(ps, 2);
        ps += __shfl_xor(ps, 4);
        ps += __shfl_xor(ps, 8);
        lrun[m][rr] = lrun[m][rr] * al + ps;
        alpha[m][rr] = al;
      }
#pragma unroll
    for (int m = 0; m < 2; ++m)
#pragma unroll
      for (int df = 0; df < 4; ++df)
#pragma unroll
        for (int rr = 0; rr < 4; ++rr) o[m][df][rr] *= alpha[m][rr];

    __syncthreads();  // WAR: previous iteration's Pt reads done
#pragma unroll
    for (int m = 0; m < 2; ++m)
#pragma unroll
      for (int n = 0; n < 4; ++n)
#pragma unroll
        for (int rr = 0; rr < 4; ++rr)
          Pt[m * 16 + qg * 4 + rr][n * 16 + qr] = (__bf16)sv[m][n][rr];
    __syncthreads();  // RAW: writes visible before reads

#pragma unroll
    for (int kc = 0; kc < 2; ++kc) {
      bf16x8 pf[2], vf[4];
#pragma unroll
      for (int m = 0; m < 2; ++m) pf[m] = *(const bf16x8*)&Pt[m * 16 + qr][kc * 32 + qg * 8];
#pragma unroll
      for (int df = 0; df < 4; ++df)
        vf[df] = *(const bf16x8*)(Vh + (size_t)(df * 16 + qr) * 2048 + kv0 + kc * 32 + qg * 8);
#pragma unroll
      for (int m = 0; m < 2; ++m)
#pragma unroll
        for (int df = 0; df < 4; ++df) o[m][df] = MFMA_BF16(pf[m], vf[df], o[m][df]);
    }
  }

  // epilogue: 1/l, gate, store attn in [b, s, h*64+d] for O GEMM
#pragma unroll
  for (int m = 0; m < 2; ++m)
#pragma unroll
    for (int rr = 0; rr < 4; ++rr) {
      const float inv = 1.f / lrun[m][rr];
      const int row = q0 + m * 16 + qg * 4 + rr;
      const size_t base = ((size_t)(b * 2048 + row)) * 1024 + h * 64;
#pragma unroll
      for (int df = 0; df < 4; ++df) {
        const int d = df * 16 + qr;
        const float g = (float)G[base + d];
        attn[base + d] = (__bf16)(o[m][df][rr] * inv * g);
      }
    }
}

// ---------------- O projection (bf16 in, fp32 out) ----------------
__global__ __launch_bounds__(256) void oproj_kernel(
    const __bf16* __restrict__ A, const __bf16* __restrict__ ow,
    const float* __restrict__ ob, float* __restrict__ C)
{
  __shared__ __bf16 As[128][64];
  __shared__ __bf16 Bs[128][64];
  const int bid = blockIdx.x;     // 256 blocks
  const int ntile = bid & 7;      // one B-panel per XCD
  const int mtile = bid >> 3;
  const int m0 = mtile * 128, n0 = ntile * 128;

  const int tid = threadIdx.x;
  const int wv = tid >> 6, ln = tid & 63;
  const int wr = wv >> 1, wc = wv & 1;
  const int qr = ln & 15, qg = ln >> 4;
  const int lrow = ln >> 3, lcol = (ln & 7) * 8;

  f32x4 acc[4][4];
#pragma unroll
  for (int m = 0; m < 4; ++m)
#pragma unroll
    for (int n = 0; n < 4; ++n) acc[m][n] = 0.f;

  for (int k0 = 0; k0 < 1024; k0 += 64) {
#pragma unroll
    for (int i = 0; i < 4; ++i) {
      const int rb = i * 32 + wv * 8;
      bf16x8 va = *(const bf16x8*)(A + (size_t)(m0 + rb + lrow) * 1024 + k0 + lcol);
      bf16x8 vb2 = *(const bf16x8*)(ow + (size_t)(n0 + rb + lrow) * 1024 + k0 + lcol);
      *(bf16x8*)&As[rb + lrow][lcol] = va;
      *(bf16x8*)&Bs[rb + lrow][lcol] = vb2;
    }
    __syncthreads();
#pragma unroll
    for (int kk = 0; kk < 2; ++kk) {
      bf16x8 af[4], bfv[4];
#pragma unroll
      for (int m = 0; m < 4; ++m) af[m] = *(const bf16x8*)&As[wr * 64 + m * 16 + qr][kk * 32 + qg * 8];
#pragma unroll
      for (int n = 0; n < 4; ++n) bfv[n] = *(const bf16x8*)&Bs[wc * 64 + n * 16 + qr][kk * 32 + qg * 8];
#pragma unroll
      for (int m = 0; m < 4; ++m)
#pragma unroll
        for (int n = 0; n < 4; ++n) acc[m][n] = MFMA_BF16(af[m], bfv[n], acc[m][n]);
    }
    __syncthreads();
  }

#pragma unroll
  for (int m = 0; m < 4; ++m) {
    const int gm0 = m0 + wr * 64 + m * 16 + qg * 4;
#pragma unroll
    for (int n = 0; n < 4; ++n) {
      const int gn = n0 + wc * 64 + n * 16 + qr;
      const float bb = ob[gn];
      float* dst = C + (size_t)gm0 * 1024 + gn;
#pragma unroll
      for (int rr = 0; rr < 4; ++rr) dst[(size_t)rr * 1024] = acc[m][n][rr] + bb;
    }
  }
}

extern "C" void kernel_launch(void* const* d_in, const int* in_sizes, int n_in,
                              void* d_out, int out_size, void* d_ws, size_t ws_size,
                              hipStream_t stream)
{
  const float* hs   = (const float*)d_in[0];
  const float* mask = (const float*)d_in[1];
  const float* qw   = (const float*)d_in[2];
  const float* qb   = (const float*)d_in[3];
  const float* kw   = (const float*)d_in[4];
  const float* kb   = (const float*)d_in[5];
  const float* vw   = (const float*)d_in[6];
  const float* vb   = (const float*)d_in[7];
  const float* ow   = (const float*)d_in[8];
  const float* ob   = (const float*)d_in[9];
  float* out = (float*)d_out;

  char* w = (char*)d_ws;
  int*    flag = (int*)w;
  __bf16* Xb  = (__bf16*)(w + 256);        // 4,194,304
  __bf16* qwb = Xb  + 4194304;             // 2,097,152
  __bf16* kwb = qwb + 2097152;             // 1,048,576
  __bf16* vwb = kwb + 1048576;             // 1,048,576
  __bf16* owb = vwb + 1048576;             // 1,048,576
  __bf16* Qo  = owb + 1048576;             // 4,194,304 (32 heads * 2048 * 64)
  __bf16* Ko  = Qo  + 4194304;
  __bf16* VTo = Ko  + 4194304;
  __bf16* Go  = VTo + 4194304;
  __bf16* At  = Go  + 4194304;

  hipMemsetAsync(flag, 0, sizeof(int), stream);
  cvt_kernel<<<1024, 256, 0, stream>>>(hs, Xb,  4194304 / 8);
  cvt_kernel<<<512,  256, 0, stream>>>(qw, qwb, 2097152 / 8);
  cvt_kernel<<<512,  256, 0, stream>>>(kw, kwb, 1048576 / 8);
  cvt_kernel<<<512,  256, 0, stream>>>(vw, vwb, 1048576 / 8);
  cvt_kernel<<<512,  256, 0, stream>>>(ow, owb, 1048576 / 8);
  maskflag_kernel<<<512, 256, 0, stream>>>((const unsigned long long*)mask, flag);
  proj_kernel<<<1024, 256, 0, stream>>>(Xb, qwb, qb, kwb, kb, vwb, vb, Qo, Ko, VTo, Go);
  attn_kernel<<<2048, 64, 0, stream>>>(Qo, Ko, VTo, Go, mask, flag, At);
  oproj_kernel<<<256, 256, 0, stream>>>(At, owb, ob, out);
}